// Round 3
// baseline (171.954 us; speedup 1.0000x reference)
//
#include <hip/hip_runtime.h>

// GCN aggregator: out[r,:] = relu( (1/25 * sum_s F[idx[r,s],:]) @ W )
// r in [0, 32768), D_IN = D_OUT = 128, S = 25.
//
// Round 6: L2-pinned gather WITHOUT line overfetch.
//  Evidence (r5b rocprof): gather was L2-line-BW-bound — 32 B rows made each
//  16 B lane-load pull a full 128 B line (4x overfetch, 840 MB @ ~19 TB/s).
//  Now G = bf16(F @ W) is stored as 8 slices of [25001][64]: (node-range p
//  0..3) x (col-half h 0..1), 3.2 MB each -> fits a 4 MiB per-XCD L2, and a
//  row is a FULL 128 B line (8 lanes x 16 B). Block chunk c = blockIdx.x % 8
//  pins slice<->XCD (verified working in r5b: FETCH ~= one pass over G).
//  A pinned block only accumulates samples with idx in its node range, so it
//  emits fp32 partials P[8][n_rows][64]; reduce_relu sums the 4 ranges.
//  Inner loop: per-row in-range indices compacted in LDS, padded to a
//  multiple of 5 with a shared zero row -> unconditional 5-deep load batches
//  (MLP>=5 saturates L2 BW per r5b), no exec-mask churn.

#define DEG 25
#define DIM 128
#define NPP 25000          // nodes per range slice (100000 / 4)
#define NPP1 25001         // slice row stride: +1 all-zero pad row

typedef __attribute__((ext_vector_type(8))) short short8;        // 8 bf16
typedef __attribute__((ext_vector_type(4))) float floatx4;       // 4 fp32
typedef __attribute__((ext_vector_type(4))) unsigned int uintx4; // 16 B

__device__ __forceinline__ unsigned short f2bf(float f) {
    // round-to-nearest-even fp32 -> bf16 (inputs finite)
    unsigned u = __float_as_uint(f);
    return (unsigned short)((u + 0x7fffu + ((u >> 16) & 1u)) >> 16);
}

// ---------------------------------------------------------------- GEMM ------
// G[p*2+h][local][64] = bf16( A[node,:] @ B[:, h*64..h*64+63] ),
// node = p*NPP + local. 128-row blocks, 4 waves, 32 rows/wave via MFMA.
#define BSTRIDE 136

__global__ __launch_bounds__(256, 2) void gemm_fw(
    const float* __restrict__ A,       // [M,128] fp32
    const float* __restrict__ B,       // [128,128] fp32
    unsigned short* __restrict__ G,    // [8][NPP1][64] bf16
    int M)
{
    __shared__ unsigned short sBt[DIM * BSTRIDE];  // B^T [n][k], 34.8 KB

    const int tid = threadIdx.x;

    // ---- stage B transposed with fp32->bf16 (once per block)
    {
        const float4* B4 = (const float4*)B;
#pragma unroll
        for (int i = 0; i < 16; ++i) {
            const int linear = i * 256 + tid;   // 0..4095 float4s
            const int k  = linear >> 5;         // B row
            const int c4 = linear & 31;         // float4 within row
            const float4 v = B4[linear];
            const int n = c4 * 4;
            sBt[(n + 0) * BSTRIDE + k] = f2bf(v.x);
            sBt[(n + 1) * BSTRIDE + k] = f2bf(v.y);
            sBt[(n + 2) * BSTRIDE + k] = f2bf(v.z);
            sBt[(n + 3) * BSTRIDE + k] = f2bf(v.w);
        }
    }
    __syncthreads();

    const int wave = tid >> 6;
    const int lane = tid & 63;
    const int quad = lane >> 4;    // 0..3
    const int l16  = lane & 15;

    const int rw0 = blockIdx.x * 128 + wave * 32;   // wave's first row

    floatx4 acc[2][8];
#pragma unroll
    for (int mt = 0; mt < 2; ++mt)
#pragma unroll
        for (int nt = 0; nt < 8; ++nt)
            acc[mt][nt] = (floatx4){0.f, 0.f, 0.f, 0.f};

#pragma unroll
    for (int kt = 0; kt < 4; ++kt) {
        const int k0 = kt * 32;

        // A-frags: lane holds A[m=l16][k=k0+quad*8+j], j=0..7.
        short8 afrag[2];
#pragma unroll
        for (int mt = 0; mt < 2; ++mt) {
            int row = rw0 + mt * 16 + l16;
            if (row >= M) row = M - 1;          // tail clamp (stores guarded)
            const float* ap = A + (size_t)row * DIM + k0 + quad * 8;
            const float4 x = *(const float4*)ap;
            const float4 y = *(const float4*)(ap + 4);
            unsigned p0 = (unsigned)f2bf(x.x) | ((unsigned)f2bf(x.y) << 16);
            unsigned p1 = (unsigned)f2bf(x.z) | ((unsigned)f2bf(x.w) << 16);
            unsigned p2 = (unsigned)f2bf(y.x) | ((unsigned)f2bf(y.y) << 16);
            unsigned p3 = (unsigned)f2bf(y.z) | ((unsigned)f2bf(y.w) << 16);
            uintx4 packed = (uintx4){p0, p1, p2, p3};
            afrag[mt] = __builtin_bit_cast(short8, packed);
        }

        // B-frags from LDS: lane holds B[k=k0+quad*8+j][n=nt*16+l16]
#pragma unroll
        for (int nt = 0; nt < 8; ++nt) {
            const uintx4 u = *(const uintx4*)&sBt[(nt * 16 + l16) * BSTRIDE + k0 + quad * 8];
            const short8 bfrag = __builtin_bit_cast(short8, u);
#pragma unroll
            for (int mt = 0; mt < 2; ++mt)
                acc[mt][nt] = __builtin_amdgcn_mfma_f32_16x16x32_bf16(
                    afrag[mt], bfrag, acc[mt][nt], 0, 0, 0);
        }
    }

    // ---- transpose C tile through LDS (reuse sBt; all B reads are done).
    // C/D frag: elem r of lane = (row 16mt+quad*4+r, col 16nt+l16).
    __syncthreads();   // everyone finished reading sBt
    {
        unsigned short* sT = sBt + wave * (32 * BSTRIDE);
#pragma unroll
        for (int mt = 0; mt < 2; ++mt)
#pragma unroll
            for (int nt = 0; nt < 8; ++nt)
#pragma unroll
                for (int r = 0; r < 4; ++r)
                    sT[(mt * 16 + quad * 4 + r) * BSTRIDE + nt * 16 + l16] =
                        f2bf(acc[mt][nt][r]);
    }
    __syncthreads();   // ordering of LDS writes vs cross-lane reads
    {
        const unsigned short* sT = sBt + wave * (32 * BSTRIDE);
        const int oct   = lane & 7;     // 16 B sub-chunk of the 128 B row
        const int nrow8 = lane >> 3;    // 0..7
        uintx4* G4 = (uintx4*)G;
#pragma unroll
        for (int g = 0; g < 4; ++g) {
            const int lrow = g * 8 + nrow8;
            const int node = rw0 + lrow;
            if (node < M) {
                const unsigned p     = (unsigned)node / NPP;     // const div
                const unsigned local = (unsigned)node - p * NPP;
#pragma unroll
                for (int h = 0; h < 2; ++h) {
                    // 8 octs x 8 nodes => 1 KB contiguous per store instr
                    const uintx4 u = *(const uintx4*)
                        &sT[lrow * BSTRIDE + h * 64 + oct * 8];
                    __builtin_nontemporal_store(u,
                        &G4[((size_t)(p * 2 + h) * NPP1 + local) * 8 + oct]);
                }
            }
        }
        // all-zero pad row (one per slice), used by the gather's padding
        if (blockIdx.x == 0 && tid < 64) {
            const int sl = tid >> 3, o = tid & 7;
            __builtin_nontemporal_store((uintx4){0, 0, 0, 0},
                &G4[((size_t)sl * NPP1 + NPP) * 8 + o]);
        }
    }
}

// ------------------------------------------------------ gather partials -----
// P[c][r][0..63] = sum over samples s of row r with idx in node-range p of
// G[c][idx-lo][0..63], c = p*2+h = blockIdx.x % 8 (pins slice<->XCD L2).
#define GRB 128

__global__ __launch_bounds__(256, 4) void gather_partial(
    const unsigned short* __restrict__ G,   // [8][NPP1][64] bf16
    const int* __restrict__ idx,            // [n_rows,25]
    float* __restrict__ P,                  // [8][n_rows][64] fp32
    int n_rows)
{
    __shared__ int sIdx[GRB * DEG];         // 12.8 KB
    __shared__ int sCnt[GRB];

    const int tid  = threadIdx.x;
    const int c    = blockIdx.x & 7;        // slice == XCD (round-robin)
    const int p    = c >> 1;
    const int rb   = blockIdx.x >> 3;
    const int row0 = rb * GRB;
    const int lo   = p * NPP;

    const int* ib = idx + (size_t)row0 * DEG;
    for (int i = tid; i < GRB * DEG; i += 256)
        sIdx[i] = __builtin_nontemporal_load(ib + i);
    __syncthreads();

    // compact each row's in-range indices (pre-subtracted), pad to x5 with
    // the slice's zero row (local == NPP). In-place is safe: cnt <= s.
    if (tid < GRB) {
        int* lp = &sIdx[tid * DEG];
        int cnt = 0;
#pragma unroll
        for (int s = 0; s < DEG; ++s) {
            const unsigned d = (unsigned)(lp[s] - lo);
            if (d < NPP) lp[cnt++] = (int)d;
        }
        const int m = ((cnt + 4) / 5) * 5;  // <= 25
        for (int i = cnt; i < m; ++i) lp[i] = NPP;
        sCnt[tid] = m;
    }
    __syncthreads();

    const int oct = tid & 7;                // 16 B sub-chunk of 128 B row
    const int rg  = tid >> 3;               // 0..31
    const uintx4* __restrict__ Gc =
        (const uintx4*)G + (size_t)c * NPP1 * 8 + oct;

#pragma unroll
    for (int rr = 0; rr < 4; ++rr) {
        const int r = rr * 32 + rg;
        const int m = sCnt[r];
        const int* lp = &sIdx[r * DEG];

        float a0 = 0.f, a1 = 0.f, a2 = 0.f, a3 = 0.f;
        float a4 = 0.f, a5 = 0.f, a6 = 0.f, a7 = 0.f;

        for (int i = 0; i < m; i += 5) {    // unconditional 5-deep batches
            const uintx4 v0 = Gc[(size_t)lp[i + 0] * 8];
            const uintx4 v1 = Gc[(size_t)lp[i + 1] * 8];
            const uintx4 v2 = Gc[(size_t)lp[i + 2] * 8];
            const uintx4 v3 = Gc[(size_t)lp[i + 3] * 8];
            const uintx4 v4 = Gc[(size_t)lp[i + 4] * 8];
#pragma unroll
            for (int k = 0; k < 5; ++k) {
                const uintx4 v = (k == 0) ? v0 : (k == 1) ? v1 :
                                 (k == 2) ? v2 : (k == 3) ? v3 : v4;
                a0 += __uint_as_float(v.x << 16);
                a1 += __uint_as_float(v.x & 0xffff0000u);
                a2 += __uint_as_float(v.y << 16);
                a3 += __uint_as_float(v.y & 0xffff0000u);
                a4 += __uint_as_float(v.z << 16);
                a5 += __uint_as_float(v.z & 0xffff0000u);
                a6 += __uint_as_float(v.w << 16);
                a7 += __uint_as_float(v.w & 0xffff0000u);
            }
        }

        floatx4* Pp = (floatx4*)P + ((size_t)c * n_rows + row0 + r) * 16 + oct * 2;
        __builtin_nontemporal_store((floatx4){a0, a1, a2, a3}, Pp);
        __builtin_nontemporal_store((floatx4){a4, a5, a6, a7}, Pp + 1);
    }
}

// --------------------------------------------------------- reduce + relu ----
// out[r][h*64+j] = relu( 1/25 * sum_p P[p*2+h][r][j] ) — streaming.
__global__ __launch_bounds__(256, 4) void reduce_relu(
    const float* __restrict__ P, float* __restrict__ out, int n_rows)
{
    const int total = n_rows * 32;          // output float4 count
    const floatx4* P4 = (const floatx4*)P;
    floatx4* o4 = (floatx4*)out;
    const float inv = 1.0f / 25.0f;
    const size_t sl = (size_t)n_rows * 16;  // slice stride in float4s

    for (int i = blockIdx.x * 256 + threadIdx.x; i < total;
         i += gridDim.x * 256) {
        const int r   = i >> 5;
        const int rem = i & 31;
        const int h   = rem >> 4;
        const int j4  = rem & 15;
        const size_t rbase = (size_t)r * 16 + j4;
        floatx4 s = __builtin_nontemporal_load(&P4[(size_t)(0 + h) * sl + rbase]);
        s = s + __builtin_nontemporal_load(&P4[(size_t)(2 + h) * sl + rbase]);
        s = s + __builtin_nontemporal_load(&P4[(size_t)(4 + h) * sl + rbase]);
        s = s + __builtin_nontemporal_load(&P4[(size_t)(6 + h) * sl + rbase]);
        const floatx4 o = {fmaxf(s.x * inv, 0.f), fmaxf(s.y * inv, 0.f),
                           fmaxf(s.z * inv, 0.f), fmaxf(s.w * inv, 0.f)};
        __builtin_nontemporal_store(o, &o4[(size_t)r * 32 + rem]);
    }
}

// --------------------------------------------- fallback (round-2 kernel) ----
#define RPB 16
#define CG 32

__device__ __forceinline__ float4 relu4(float4 v) {
    return make_float4(fmaxf(v.x, 0.f), fmaxf(v.y, 0.f),
                       fmaxf(v.z, 0.f), fmaxf(v.w, 0.f));
}

__global__ __launch_bounds__(256, 4) void gcn_fused(
    const float* __restrict__ F, const int* __restrict__ idx,
    const float* __restrict__ W, float* __restrict__ out, int n_rows)
{
    __shared__ float4 sV[RPB * CG];
    __shared__ int    sIdx[RPB * DEG];

    const float4* F4 = (const float4*)F;
    const float4* W4 = (const float4*)W;
    float4* out4 = (float4*)out;

    const int tid = threadIdx.x;
    const int row0 = blockIdx.x * RPB;

    for (int i = tid; i < RPB * DEG; i += 256)
        sIdx[i] = idx[(size_t)row0 * DEG + i];
    __syncthreads();

    const int cg = tid & 31;
    const int rs = tid >> 5;

#pragma unroll
    for (int rr = 0; rr < 2; ++rr) {
        const int r = rs + rr * 8;
        int j[DEG];
#pragma unroll
        for (int s = 0; s < DEG; ++s) j[s] = sIdx[r * DEG + s];
        float4 acc = make_float4(0.f, 0.f, 0.f, 0.f);
#pragma unroll
        for (int s = 0; s < DEG; ++s) {
            float4 f = F4[(size_t)j[s] * CG + cg];
            acc.x += f.x; acc.y += f.y; acc.z += f.z; acc.w += f.w;
        }
        const float inv = 1.0f / 25.0f;
        acc.x *= inv; acc.y *= inv; acc.z *= inv; acc.w *= inv;
        sV[r * CG + cg] = acc;
    }
    __syncthreads();

    const float4* vA = &sV[rs * CG];
    const float4* vB = &sV[(rs + 8) * CG];
    float4 o0 = make_float4(0.f, 0.f, 0.f, 0.f);
    float4 o1 = make_float4(0.f, 0.f, 0.f, 0.f);
#pragma unroll 4
    for (int d4 = 0; d4 < CG; ++d4) {
        const float4 a = vA[d4];
        const float4 b = vB[d4];
        const float4 w0 = W4[(size_t)(4 * d4 + 0) * CG + cg];
        const float4 w1 = W4[(size_t)(4 * d4 + 1) * CG + cg];
        const float4 w2 = W4[(size_t)(4 * d4 + 2) * CG + cg];
        const float4 w3 = W4[(size_t)(4 * d4 + 3) * CG + cg];
        o0.x += a.x*w0.x + a.y*w1.x + a.z*w2.x + a.w*w3.x;
        o0.y += a.x*w0.y + a.y*w1.y + a.z*w2.y + a.w*w3.y;
        o0.z += a.x*w0.z + a.y*w1.z + a.z*w2.z + a.w*w3.z;
        o0.w += a.x*w0.w + a.y*w1.w + a.z*w2.w + a.w*w3.w;
        o1.x += b.x*w0.x + b.y*w1.x + b.z*w2.x + b.w*w3.x;
        o1.y += b.x*w0.y + b.y*w1.y + b.z*w2.y + b.w*w3.y;
        o1.z += b.x*w0.z + b.y*w1.z + b.z*w2.z + b.w*w3.z;
        o1.w += b.x*w0.w + b.y*w1.w + b.z*w2.w + b.w*w3.w;
    }
    out4[(size_t)(row0 + rs) * CG + cg]     = relu4(o0);
    out4[(size_t)(row0 + rs + 8) * CG + cg] = relu4(o1);
}

// ----------------------------------------------------------------------------
extern "C" void kernel_launch(void* const* d_in, const int* in_sizes, int n_in,
                              void* d_out, int out_size, void* d_ws, size_t ws_size,
                              hipStream_t stream) {
    const float* F   = (const float*)d_in[0];   // features [100000,128] fp32
    const int*   idx = (const int*)d_in[1];     // sample_res [8,4096,25] int32
    const float* W   = (const float*)d_in[2];   // weights [128,128] fp32
    float* out = (float*)d_out;                 // [8,4096,128] fp32

    const int n_nodes = in_sizes[0] / DIM;      // 100000
    const int n_rows  = in_sizes[1] / DEG;      // 32768

    const size_t gbytes = (size_t)8 * NPP1 * 64 * sizeof(unsigned short);
    const size_t poff   = (gbytes + 1023) & ~(size_t)1023;
    const size_t need   = poff + (size_t)8 * n_rows * 64 * sizeof(float);

    if (n_nodes == 100000 && ws_size >= need && (n_rows & (GRB - 1)) == 0) {
        unsigned short* G = (unsigned short*)d_ws;
        float* P = (float*)((char*)d_ws + poff);
        gemm_fw<<<(n_nodes + 127) / 128, 256, 0, stream>>>(F, W, G, n_nodes);
        gather_partial<<<(n_rows / GRB) * 8, 256, 0, stream>>>(G, idx, P, n_rows);
        reduce_relu<<<1024, 256, 0, stream>>>(P, out, n_rows);
    } else {
        gcn_fused<<<n_rows / RPB, 256, 0, stream>>>(F, idx, W, out, n_rows);
    }
}

// Round 4
// 128.632 us; speedup vs baseline: 1.3368x; 1.3368x over previous
//
#include <hip/hip_runtime.h>

// GCN aggregator: out[r,:] = relu( (1/25 * sum_s F[idx[r,s],:]) @ W )
// r in [0, 32768), D_IN = D_OUT = 128, S = 25.
//
// Round 7: TEMPORAL slice phasing + register accumulation.
//  r6 post-mortem: spatial node-range pinning forced fp32 partials to HBM
//  (112 MB WRITE) + an extra reduce pass — that traffic was the regression.
//  Now: G = bf16(F @ W) stays in 8 slices [NPP1][64] = (range p 0..3) x
//  (col-half h 0..1), 3.2 MB each. The gather grid (1024 blocks = 4/CU,
//  fully co-resident) sweeps ranges p=0..3 in the SAME order in lockstep-ish
//  phases; during phase p every XCD's L2 holds slice (p,h) (3.2 MB < 4 MiB).
//  h is spatial (blockIdx&1 <-> XCD parity) so each XCD only ever touches
//  its 4 h-slices: ~102 MB of sequential L3->L2 fill + 210 MB of full-line
//  L2 hits, and ZERO partial-sum traffic: each thread keeps its rows' fp32
//  sums in registers across phases and writes out once with relu.
//  Per-row per-range index lists are compacted once into LDS, padded to a
//  multiple of 5 with the slice's zero row -> unconditional 5-deep batches.

#define DEG 25
#define DIM 128
#define NPP 25000          // nodes per range slice (100000 / 4)
#define NPP1 25001         // slice row stride: +1 all-zero pad row

typedef __attribute__((ext_vector_type(8))) short short8;        // 8 bf16
typedef __attribute__((ext_vector_type(4))) float floatx4;       // 4 fp32
typedef __attribute__((ext_vector_type(4))) unsigned int uintx4; // 16 B

__device__ __forceinline__ unsigned short f2bf(float f) {
    // round-to-nearest-even fp32 -> bf16 (inputs finite)
    unsigned u = __float_as_uint(f);
    return (unsigned short)((u + 0x7fffu + ((u >> 16) & 1u)) >> 16);
}

// ---------------------------------------------------------------- GEMM ------
// G[p*2+h][local][64] = bf16( A[node,:] @ B[:, h*64..h*64+63] ),
// node = p*NPP + local. 128-row blocks, 4 waves, 32 rows/wave via MFMA.
#define BSTRIDE 136

__global__ __launch_bounds__(256, 2) void gemm_fw(
    const float* __restrict__ A,       // [M,128] fp32
    const float* __restrict__ B,       // [128,128] fp32
    unsigned short* __restrict__ G,    // [8][NPP1][64] bf16
    int M)
{
    __shared__ unsigned short sBt[DIM * BSTRIDE];  // B^T [n][k], 34.8 KB

    const int tid = threadIdx.x;

    // ---- stage B transposed with fp32->bf16 (once per block)
    {
        const float4* B4 = (const float4*)B;
#pragma unroll
        for (int i = 0; i < 16; ++i) {
            const int linear = i * 256 + tid;   // 0..4095 float4s
            const int k  = linear >> 5;         // B row
            const int c4 = linear & 31;         // float4 within row
            const float4 v = B4[linear];
            const int n = c4 * 4;
            sBt[(n + 0) * BSTRIDE + k] = f2bf(v.x);
            sBt[(n + 1) * BSTRIDE + k] = f2bf(v.y);
            sBt[(n + 2) * BSTRIDE + k] = f2bf(v.z);
            sBt[(n + 3) * BSTRIDE + k] = f2bf(v.w);
        }
    }
    __syncthreads();

    const int wave = tid >> 6;
    const int lane = tid & 63;
    const int quad = lane >> 4;    // 0..3
    const int l16  = lane & 15;

    const int rw0 = blockIdx.x * 128 + wave * 32;   // wave's first row

    floatx4 acc[2][8];
#pragma unroll
    for (int mt = 0; mt < 2; ++mt)
#pragma unroll
        for (int nt = 0; nt < 8; ++nt)
            acc[mt][nt] = (floatx4){0.f, 0.f, 0.f, 0.f};

#pragma unroll
    for (int kt = 0; kt < 4; ++kt) {
        const int k0 = kt * 32;

        // A-frags: lane holds A[m=l16][k=k0+quad*8+j], j=0..7.
        short8 afrag[2];
#pragma unroll
        for (int mt = 0; mt < 2; ++mt) {
            int row = rw0 + mt * 16 + l16;
            if (row >= M) row = M - 1;          // tail clamp (stores guarded)
            const float* ap = A + (size_t)row * DIM + k0 + quad * 8;
            const float4 x = *(const float4*)ap;
            const float4 y = *(const float4*)(ap + 4);
            unsigned p0 = (unsigned)f2bf(x.x) | ((unsigned)f2bf(x.y) << 16);
            unsigned p1 = (unsigned)f2bf(x.z) | ((unsigned)f2bf(x.w) << 16);
            unsigned p2 = (unsigned)f2bf(y.x) | ((unsigned)f2bf(y.y) << 16);
            unsigned p3 = (unsigned)f2bf(y.z) | ((unsigned)f2bf(y.w) << 16);
            uintx4 packed = (uintx4){p0, p1, p2, p3};
            afrag[mt] = __builtin_bit_cast(short8, packed);
        }

        // B-frags from LDS: lane holds B[k=k0+quad*8+j][n=nt*16+l16]
#pragma unroll
        for (int nt = 0; nt < 8; ++nt) {
            const uintx4 u = *(const uintx4*)&sBt[(nt * 16 + l16) * BSTRIDE + k0 + quad * 8];
            const short8 bfrag = __builtin_bit_cast(short8, u);
#pragma unroll
            for (int mt = 0; mt < 2; ++mt)
                acc[mt][nt] = __builtin_amdgcn_mfma_f32_16x16x32_bf16(
                    afrag[mt], bfrag, acc[mt][nt], 0, 0, 0);
        }
    }

    // ---- transpose C tile through LDS (reuse sBt; all B reads are done).
    // C/D frag: elem r of lane = (row 16mt+quad*4+r, col 16nt+l16).
    __syncthreads();   // everyone finished reading sBt
    {
        unsigned short* sT = sBt + wave * (32 * BSTRIDE);
#pragma unroll
        for (int mt = 0; mt < 2; ++mt)
#pragma unroll
            for (int nt = 0; nt < 8; ++nt)
#pragma unroll
                for (int r = 0; r < 4; ++r)
                    sT[(mt * 16 + quad * 4 + r) * BSTRIDE + nt * 16 + l16] =
                        f2bf(acc[mt][nt][r]);
    }
    __syncthreads();   // ordering of LDS writes vs cross-lane reads
    {
        const unsigned short* sT = sBt + wave * (32 * BSTRIDE);
        const int oct   = lane & 7;     // 16 B sub-chunk of the 128 B row
        const int nrow8 = lane >> 3;    // 0..7
        uintx4* G4 = (uintx4*)G;
#pragma unroll
        for (int g = 0; g < 4; ++g) {
            const int lrow = g * 8 + nrow8;
            const int node = rw0 + lrow;
            if (node < M) {
                const unsigned p     = (unsigned)node / NPP;     // const div
                const unsigned local = (unsigned)node - p * NPP;
#pragma unroll
                for (int h = 0; h < 2; ++h) {
                    // 8 octs x 8 nodes => 1 KB contiguous per store instr
                    const uintx4 u = *(const uintx4*)
                        &sT[lrow * BSTRIDE + h * 64 + oct * 8];
                    __builtin_nontemporal_store(u,
                        &G4[((size_t)(p * 2 + h) * NPP1 + local) * 8 + oct]);
                }
            }
        }
        // all-zero pad row (one per slice), used by the gather's padding
        if (blockIdx.x == 0 && tid < 64) {
            const int sl = tid >> 3, o = tid & 7;
            __builtin_nontemporal_store((uintx4){0, 0, 0, 0},
                &G4[((size_t)sl * NPP1 + NPP) * 8 + o]);
        }
    }
}

// -------------------------------------------------- phased gather-mean-relu -
// out[r][h*64 + 0..63] = relu( 1/25 * sum_p sum_{s: idx in range p}
//                               G[p*2+h][idx - p*NPP][0..63] )
// h = blockIdx&1 (spatial: XCD parity); p swept in phases by ALL blocks in
// the same order -> per-phase L2 working set = one 3.2 MB slice per XCD.
// Accumulators live in registers across phases; single store at the end.
#define GRB 64

__global__ __launch_bounds__(256, 4) void gather_phased(
    const unsigned short* __restrict__ G,   // [8][NPP1][64] bf16
    const int* __restrict__ idx,            // [n_rows,25]
    float* __restrict__ out,                // [n_rows,128] fp32
    int n_rows)
{
    __shared__ int sRaw[GRB * DEG];         // 6.4 KB
    __shared__ int sC[GRB][4][25];          // 25.6 KB compacted per-range
    __shared__ int sCnt[GRB][4];            // padded counts (multiple of 5)

    const int tid  = threadIdx.x;
    const int h    = blockIdx.x & 1;        // col-half == XCD parity
    const int rb   = blockIdx.x >> 1;
    const int row0 = rb * GRB;

    const int* ib = idx + (size_t)row0 * DEG;
    for (int i = tid; i < GRB * DEG; i += 256)
        sRaw[i] = __builtin_nontemporal_load(ib + i);
    __syncthreads();

    // compaction: one thread per (row, range). The 4 range-threads of a row
    // read the same sRaw words (LDS broadcast, free).
    {
        const int row = tid >> 2;
        const int rg  = tid & 3;
        const int lo  = rg * NPP;
        int* dst = &sC[row][rg][0];
        int cnt = 0;
#pragma unroll
        for (int s = 0; s < DEG; ++s) {
            const unsigned d = (unsigned)(sRaw[row * DEG + s] - lo);
            if (d < NPP) dst[cnt++] = (int)d;
        }
        const int m = ((cnt + 4) / 5) * 5;  // <= 25
        for (int i = cnt; i < m; ++i) dst[i] = NPP;  // slice's zero row
        sCnt[row][rg] = m;
    }
    __syncthreads();

    const int oct   = tid & 7;              // 16 B sub-chunk of 128 B row
    const int rslot = tid >> 3;             // 0..31

    float acc[2][8];
#pragma unroll
    for (int rr = 0; rr < 2; ++rr)
#pragma unroll
        for (int j = 0; j < 8; ++j) acc[rr][j] = 0.f;

    for (int p = 0; p < 4; ++p) {           // temporal phases, same order
        const uintx4* __restrict__ Gc =
            (const uintx4*)G + (size_t)(p * 2 + h) * NPP1 * 8 + oct;
#pragma unroll
        for (int rr = 0; rr < 2; ++rr) {
            const int r = rslot + rr * 32;
            const int m = sCnt[r][p];
            const int* lp = &sC[r][p][0];
            for (int i = 0; i < m; i += 5) {    // unconditional 5-deep
                const uintx4 v0 = Gc[(size_t)lp[i + 0] * 8];
                const uintx4 v1 = Gc[(size_t)lp[i + 1] * 8];
                const uintx4 v2 = Gc[(size_t)lp[i + 2] * 8];
                const uintx4 v3 = Gc[(size_t)lp[i + 3] * 8];
                const uintx4 v4 = Gc[(size_t)lp[i + 4] * 8];
#pragma unroll
                for (int k = 0; k < 5; ++k) {
                    const uintx4 v = (k == 0) ? v0 : (k == 1) ? v1 :
                                     (k == 2) ? v2 : (k == 3) ? v3 : v4;
                    acc[rr][0] += __uint_as_float(v.x << 16);
                    acc[rr][1] += __uint_as_float(v.x & 0xffff0000u);
                    acc[rr][2] += __uint_as_float(v.y << 16);
                    acc[rr][3] += __uint_as_float(v.y & 0xffff0000u);
                    acc[rr][4] += __uint_as_float(v.z << 16);
                    acc[rr][5] += __uint_as_float(v.z & 0xffff0000u);
                    acc[rr][6] += __uint_as_float(v.w << 16);
                    acc[rr][7] += __uint_as_float(v.w & 0xffff0000u);
                }
            }
        }
    }

    const float inv = 1.0f / 25.0f;
#pragma unroll
    for (int rr = 0; rr < 2; ++rr) {
        const int r = rslot + rr * 32;
        // 8 octs x 32 B = 256 B contiguous per row-half
        floatx4* op = (floatx4*)(out + (size_t)(row0 + r) * DIM + h * 64 + oct * 8);
        const floatx4 o0 = {fmaxf(acc[rr][0] * inv, 0.f), fmaxf(acc[rr][1] * inv, 0.f),
                            fmaxf(acc[rr][2] * inv, 0.f), fmaxf(acc[rr][3] * inv, 0.f)};
        const floatx4 o1 = {fmaxf(acc[rr][4] * inv, 0.f), fmaxf(acc[rr][5] * inv, 0.f),
                            fmaxf(acc[rr][6] * inv, 0.f), fmaxf(acc[rr][7] * inv, 0.f)};
        __builtin_nontemporal_store(o0, op);
        __builtin_nontemporal_store(o1, op + 1);
    }
}

// --------------------------------------------- fallback (round-2 kernel) ----
#define RPB 16
#define CG 32

__device__ __forceinline__ float4 relu4(float4 v) {
    return make_float4(fmaxf(v.x, 0.f), fmaxf(v.y, 0.f),
                       fmaxf(v.z, 0.f), fmaxf(v.w, 0.f));
}

__global__ __launch_bounds__(256, 4) void gcn_fused(
    const float* __restrict__ F, const int* __restrict__ idx,
    const float* __restrict__ W, float* __restrict__ out, int n_rows)
{
    __shared__ float4 sV[RPB * CG];
    __shared__ int    sIdx[RPB * DEG];

    const float4* F4 = (const float4*)F;
    const float4* W4 = (const float4*)W;
    float4* out4 = (float4*)out;

    const int tid = threadIdx.x;
    const int row0 = blockIdx.x * RPB;

    for (int i = tid; i < RPB * DEG; i += 256)
        sIdx[i] = idx[(size_t)row0 * DEG + i];
    __syncthreads();

    const int cg = tid & 31;
    const int rs = tid >> 5;

#pragma unroll
    for (int rr = 0; rr < 2; ++rr) {
        const int r = rs + rr * 8;
        int j[DEG];
#pragma unroll
        for (int s = 0; s < DEG; ++s) j[s] = sIdx[r * DEG + s];
        float4 acc = make_float4(0.f, 0.f, 0.f, 0.f);
#pragma unroll
        for (int s = 0; s < DEG; ++s) {
            float4 f = F4[(size_t)j[s] * CG + cg];
            acc.x += f.x; acc.y += f.y; acc.z += f.z; acc.w += f.w;
        }
        const float inv = 1.0f / 25.0f;
        acc.x *= inv; acc.y *= inv; acc.z *= inv; acc.w *= inv;
        sV[r * CG + cg] = acc;
    }
    __syncthreads();

    const float4* vA = &sV[rs * CG];
    const float4* vB = &sV[(rs + 8) * CG];
    float4 o0 = make_float4(0.f, 0.f, 0.f, 0.f);
    float4 o1 = make_float4(0.f, 0.f, 0.f, 0.f);
#pragma unroll 4
    for (int d4 = 0; d4 < CG; ++d4) {
        const float4 a = vA[d4];
        const float4 b = vB[d4];
        const float4 w0 = W4[(size_t)(4 * d4 + 0) * CG + cg];
        const float4 w1 = W4[(size_t)(4 * d4 + 1) * CG + cg];
        const float4 w2 = W4[(size_t)(4 * d4 + 2) * CG + cg];
        const float4 w3 = W4[(size_t)(4 * d4 + 3) * CG + cg];
        o0.x += a.x*w0.x + a.y*w1.x + a.z*w2.x + a.w*w3.x;
        o0.y += a.x*w0.y + a.y*w1.y + a.z*w2.y + a.w*w3.y;
        o0.z += a.x*w0.z + a.y*w1.z + a.z*w2.z + a.w*w3.z;
        o0.w += a.x*w0.w + a.y*w1.w + a.z*w2.w + a.w*w3.w;
        o1.x += b.x*w0.x + b.y*w1.x + b.z*w2.x + b.w*w3.x;
        o1.y += b.x*w0.y + b.y*w1.y + b.z*w2.y + b.w*w3.y;
        o1.z += b.x*w0.z + b.y*w1.z + b.z*w2.z + b.w*w3.z;
        o1.w += b.x*w0.w + b.y*w1.w + b.z*w2.w + b.w*w3.w;
    }
    out4[(size_t)(row0 + rs) * CG + cg]     = relu4(o0);
    out4[(size_t)(row0 + rs + 8) * CG + cg] = relu4(o1);
}

// ----------------------------------------------------------------------------
extern "C" void kernel_launch(void* const* d_in, const int* in_sizes, int n_in,
                              void* d_out, int out_size, void* d_ws, size_t ws_size,
                              hipStream_t stream) {
    const float* F   = (const float*)d_in[0];   // features [100000,128] fp32
    const int*   idx = (const int*)d_in[1];     // sample_res [8,4096,25] int32
    const float* W   = (const float*)d_in[2];   // weights [128,128] fp32
    float* out = (float*)d_out;                 // [8,4096,128] fp32

    const int n_nodes = in_sizes[0] / DIM;      // 100000
    const int n_rows  = in_sizes[1] / DEG;      // 32768

    const size_t need = (size_t)8 * NPP1 * 64 * sizeof(unsigned short);

    if (n_nodes == 100000 && ws_size >= need && (n_rows & (GRB - 1)) == 0) {
        unsigned short* G = (unsigned short*)d_ws;
        gemm_fw<<<(n_nodes + 127) / 128, 256, 0, stream>>>(F, W, G, n_nodes);
        gather_phased<<<(n_rows / GRB) * 2, 256, 0, stream>>>(G, idx, out, n_rows);
    } else {
        gcn_fused<<<n_rows / RPB, 256, 0, stream>>>(F, idx, W, out, n_rows);
    }
}